// Round 9
// baseline (111.936 us; speedup 1.0000x reference)
//
#include <hip/hip_runtime.h>

// out[b, p] = sum_s prob[b,s] * param[p, idx[b,s]]
//   param: (512*2048, 64) fp32 = 256 MiB ; out: (64, 512*2048) fp32 = 256 MiB
// Floor ~= 537 MB / 6.29 TB/s (measured mixed R+W copy ceiling) ~= 85 us.
//
// Round 9: R3 skeleton, TILE=512 / BLK=1024 / 128 KiB LDS (1 block/CU,
// 16 waves/CU -- same wave count as R3). Mechanism being tested: per-batch
// write-burst granularity. Chunk-size ladder so far (>=16 waves/CU):
//   128 B -> 116.6us (R4) | 512 B -> 100.5us (R8) | 1 KiB -> 96.25us (R3)
// This gives each (wave,batch) a contiguous 2 KiB store burst (2 consecutive
// dwordx4 instructions), 4 batches per wave.
//
// LDS layout: bank-major + XOR swizzle, word(k,p) = k*512 + (p ^ f(k)),
// f(k) = ((k>>2)&7)<<2.
//   staging writes: per instruction, 32 banks x 2 lanes -> free
//   gather: ds_read_b128 at pw=lane*4 (+h*256; bit 8 disjoint from XOR bits)
//           -> uniform 8 words/bank = b128 minimum, conflict-free
//   stores: 2 consecutive dwordx4 -> 2 KiB contiguous per (wave,batch)

#define NPOS   (512 * 2048)
#define NBANK  64
#define NBATCH 64
#define TILE   512
#define BLK    1024
#define NBLK   (NPOS / TILE)   // 2048 blocks

typedef float f32x4 __attribute__((ext_vector_type(4)));
typedef int   i32x4 __attribute__((ext_vector_type(4)));

__global__ __launch_bounds__(BLK, 4) void vparam_kernel(
    const float* __restrict__ param,
    const int*   __restrict__ sel,
    const float* __restrict__ prob,
    float*       __restrict__ out)
{
    __shared__ float lds[NBANK * TILE];   // 128 KiB -> 1 block/CU, 16 waves

    const int tid       = threadIdx.x;
    const int wave      = tid >> 6;       // 0..15
    const int lane      = tid & 63;
    const int tile_base = blockIdx.x * TILE;

    // ---- Stage: global (position-major) -> LDS (bank-major, swizzled) ----
    const f32x4* g4 = (const f32x4*)(param + (size_t)tile_base * NBANK);
    const int k0 = (tid & 15) * 4;        // first of 4 consecutive banks
    const int f  = (tid & 7) << 2;        // = f(k) for k in [k0, k0+4)
    const int sp = tid >> 4;              // 0..63
    #pragma unroll
    for (int i = 0; i < 8; ++i) {
        f32x4 v = __builtin_nontemporal_load(&g4[i * BLK + tid]); // 1 KiB/wave
        int p = i * 64 + sp;              // position within tile
        #pragma unroll
        for (int j = 0; j < 4; ++j)
            lds[(k0 + j) * TILE + (p ^ f)] = v[j];   // 2 lanes/bank -> free
    }
    __syncthreads();   // vmcnt drain = own staging loads only (all needed);
                       // CU stays fed: 128 KiB reads in flight + prior stores

    // ---- Gather: b128 LDS reads, 2 KiB contiguous store per (wave,batch) ----
    const i32x4* sel4  = (const i32x4*)sel;    // uniform b -> s_load
    const f32x4* prob4 = (const f32x4*)prob;
    const int pw = lane * 4;              // lane's 4 positions (words)

    #pragma unroll
    for (int j = 0; j < 4; ++j) {
        int b = __builtin_amdgcn_readfirstlane(wave * 4 + j);
        i32x4 iv = sel4[b];
        f32x4 wv = prob4[b];
        float* orow = out + (size_t)b * NPOS + tile_base;
        const int fx = ((iv.x >> 2) & 7) << 2;
        const int fy = ((iv.y >> 2) & 7) << 2;
        const int fz = ((iv.z >> 2) & 7) << 2;
        const int fw = ((iv.w >> 2) & 7) << 2;
        #pragma unroll
        for (int h = 0; h < 2; ++h) {     // two 1 KiB halves -> 2 KiB burst
            const int hb = h * 256;
            f32x4 a0 = *(const f32x4*)&lds[iv.x * TILE + hb + (pw ^ fx)];
            f32x4 a1 = *(const f32x4*)&lds[iv.y * TILE + hb + (pw ^ fy)];
            f32x4 a2 = *(const f32x4*)&lds[iv.z * TILE + hb + (pw ^ fz)];
            f32x4 a3 = *(const f32x4*)&lds[iv.w * TILE + hb + (pw ^ fw)];
            f32x4 acc = a0 * wv.x + a1 * wv.y + a2 * wv.z + a3 * wv.w;
            __builtin_nontemporal_store(acc, (f32x4*)(orow + hb) + lane);
        }
    }
}

extern "C" void kernel_launch(void* const* d_in, const int* in_sizes, int n_in,
                              void* d_out, int out_size, void* d_ws, size_t ws_size,
                              hipStream_t stream) {
    const float* param = (const float*)d_in[0];
    const int*   sel   = (const int*)d_in[1];
    const float* prob  = (const float*)d_in[2];
    float*       out   = (float*)d_out;

    vparam_kernel<<<dim3(NBLK), dim3(BLK), 0, stream>>>(param, sel, prob, out);
}

// Round 10
// 100.973 us; speedup vs baseline: 1.1086x; 1.1086x over previous
//
#include <hip/hip_runtime.h>

// out[b, p] = sum_s prob[b,s] * param[p, idx[b,s]]
//   param: (512*2048, 64) fp32 = 256 MiB ; out: (64, 512*2048) fp32 = 256 MiB
// Floor ~= 537 MB / 6.29 TB/s (measured mixed R+W copy ceiling) ~= 85 us.
//
// Round 10 = round 3 (best: 96.25 us) + bijective XCD-aware block swizzle.
// R3 is the LDS-constrained optimum of the family: 64 KiB staging buffer
// (largest giving 2 blocks/CU for barber-pole phase coverage), 1 KiB/wave
// store chunks (512B->100.5, 1KiB->96.25, 2KiB@1blk->111.9), one barrier
// per block placed before any store is issued.
// Swizzle mechanism: consecutive blockIdx round-robin across XCDs; remap
// tile = (orig&7)*512 + orig>>3 so each XCD reads one contiguous 32-MiB
// param region in order and its ~64 resident blocks span adjacent tiles ->
// per-batch write streams become dense sliding windows per XCD instead of
// 8-KiB-strided 1-KiB chunks. Pure index remap; patterns otherwise identical.

#define NPOS   (512 * 2048)
#define NBANK  64
#define NBATCH 64
#define TILE   256
#define BLK    512
#define NBLK   (NPOS / TILE)   // 4096 blocks, divisible by 8

typedef float f32x4 __attribute__((ext_vector_type(4)));
typedef int   i32x4 __attribute__((ext_vector_type(4)));

__global__ __launch_bounds__(BLK, 4) void vparam_kernel(
    const float* __restrict__ param,
    const int*   __restrict__ sel,
    const float* __restrict__ prob,
    float*       __restrict__ out)
{
    __shared__ float lds[NBANK * TILE];   // 64 KiB -> 2 blocks/CU

    const int tid = threadIdx.x;

    // XCD-aware swizzle: xcd = orig % 8 gets contiguous tile range
    const int orig      = blockIdx.x;
    const int tile_idx  = (orig & 7) * (NBLK / 8) + (orig >> 3);
    const int tile_base = tile_idx * TILE;

    // ---- Stage: global (position-major) -> LDS (bank-major, swizzled) ----
    const f32x4* g4 = (const f32x4*)(param + (size_t)tile_base * NBANK);
    #pragma unroll
    for (int i = 0; i < 8; ++i) {
        f32x4 v = __builtin_nontemporal_load(&g4[i * BLK + tid]); // 1 KiB/wave, coalesced
        int p  = i * 32 + (tid >> 4);       // position within tile
        int k0 = (tid & 15) * 4;            // first of 4 consecutive banks
        #pragma unroll
        for (int j = 0; j < 4; ++j) {
            int k = k0 + j;
            lds[k * TILE + (p ^ (k & 28))] = v[j];   // 2 lanes/bank -> free
        }
    }
    __syncthreads();   // drains only this block's own (needed) staging loads

    // ---- Gather: wave-uniform banks, b128 reads, float4 nt stores ----
    const int wave = tid >> 6;               // 0..7
    const int lane = tid & 63;
    const int pw   = lane * 4;               // lane's 4 positions (word offset)
    const i32x4* sel4  = (const i32x4*)sel;
    const f32x4* prob4 = (const f32x4*)prob;

    #pragma unroll
    for (int j = 0; j < 8; ++j) {
        int b = __builtin_amdgcn_readfirstlane(wave * 8 + j);   // -> s_load
        i32x4 iv = sel4[b];
        f32x4 wv = prob4[b];
        const f32x4 a0 = *(const f32x4*)&lds[iv.x * TILE + (pw ^ (iv.x & 28))];
        const f32x4 a1 = *(const f32x4*)&lds[iv.y * TILE + (pw ^ (iv.y & 28))];
        const f32x4 a2 = *(const f32x4*)&lds[iv.z * TILE + (pw ^ (iv.z & 28))];
        const f32x4 a3 = *(const f32x4*)&lds[iv.w * TILE + (pw ^ (iv.w & 28))];
        f32x4 acc = a0 * wv.x + a1 * wv.y + a2 * wv.z + a3 * wv.w;
        f32x4* o = (f32x4*)(out + (size_t)b * NPOS + tile_base);
        __builtin_nontemporal_store(acc, &o[lane]);  // 1 KiB/wave, coalesced
    }
}

extern "C" void kernel_launch(void* const* d_in, const int* in_sizes, int n_in,
                              void* d_out, int out_size, void* d_ws, size_t ws_size,
                              hipStream_t stream) {
    const float* param = (const float*)d_in[0];
    const int*   sel   = (const int*)d_in[1];
    const float* prob  = (const float*)d_in[2];
    float*       out   = (float*)d_out;

    vparam_kernel<<<dim3(NBLK), dim3(BLK), 0, stream>>>(param, sel, prob, out);
}

// Round 11
// 88.075 us; speedup vs baseline: 1.2709x; 1.1464x over previous
//
#include <hip/hip_runtime.h>

// out[b, p] = sum_s prob[b,s] * param[p, idx[b,s]]
//   param: (512*2048, 64) fp32 = 256 MiB ; out: (64, 512*2048) fp32 = 256 MiB
// Floor ~= 537 MB / 6.29 TB/s (measured mixed R+W copy ceiling) ~= 85 us.
//
// Round 11 = round 3 (best: 96.25 us) with ONE change: output stores are
// REGULAR (cached) instead of nontemporal. Mechanism: the R4/R8/R3 chunk
// ladder (128B->116.6, 512B->100.5, 1KiB->96.25) proved the residual is
// DRAM write-burst efficiency across 64 interleaved 4-MiB-apart streams.
// nt stores push 1-KiB bursts straight toward DRAM; cached stores let the
// 4-MiB/XCD L2 aggregate dirty lines from many blocks and schedule larger,
// better-sequenced writebacks. param loads stay nontemporal (streamed once,
// no reuse) so they don't fight the write data for L2 capacity.
// Everything else byte-identical to R3: TILE=256/BLK=512, 64 KiB LDS
// (2 blocks/CU barber-pole), verified conflict-free bank-major XOR-swizzle,
// b128 gather reads, 1 KiB/wave coalesced stores, single barrier placed
// before any store is issued.

#define NPOS   (512 * 2048)
#define NBANK  64
#define NBATCH 64
#define TILE   256
#define BLK    512

typedef float f32x4 __attribute__((ext_vector_type(4)));
typedef int   i32x4 __attribute__((ext_vector_type(4)));

__global__ __launch_bounds__(BLK, 4) void vparam_kernel(
    const float* __restrict__ param,
    const int*   __restrict__ sel,
    const float* __restrict__ prob,
    float*       __restrict__ out)
{
    __shared__ float lds[NBANK * TILE];   // 64 KiB -> 2 blocks/CU

    const int tid       = threadIdx.x;
    const int tile_base = blockIdx.x * TILE;

    // ---- Stage: global (position-major) -> LDS (bank-major, swizzled) ----
    const f32x4* g4 = (const f32x4*)(param + (size_t)tile_base * NBANK);
    #pragma unroll
    for (int i = 0; i < 8; ++i) {
        f32x4 v = __builtin_nontemporal_load(&g4[i * BLK + tid]); // 1 KiB/wave, coalesced
        int p  = i * 32 + (tid >> 4);       // position within tile
        int k0 = (tid & 15) * 4;            // first of 4 consecutive banks
        #pragma unroll
        for (int j = 0; j < 4; ++j) {
            int k = k0 + j;
            lds[k * TILE + (p ^ (k & 28))] = v[j];   // 2 lanes/bank -> free
        }
    }
    __syncthreads();   // drains only this block's own (needed) staging loads

    // ---- Gather: wave-uniform banks, b128 reads, float4 cached stores ----
    const int wave = tid >> 6;               // 0..7
    const int lane = tid & 63;
    const int pw   = lane * 4;               // lane's 4 positions (word offset)
    const i32x4* sel4  = (const i32x4*)sel;
    const f32x4* prob4 = (const f32x4*)prob;

    #pragma unroll
    for (int j = 0; j < 8; ++j) {
        int b = __builtin_amdgcn_readfirstlane(wave * 8 + j);   // -> s_load
        i32x4 iv = sel4[b];
        f32x4 wv = prob4[b];
        const f32x4 a0 = *(const f32x4*)&lds[iv.x * TILE + (pw ^ (iv.x & 28))];
        const f32x4 a1 = *(const f32x4*)&lds[iv.y * TILE + (pw ^ (iv.y & 28))];
        const f32x4 a2 = *(const f32x4*)&lds[iv.z * TILE + (pw ^ (iv.z & 28))];
        const f32x4 a3 = *(const f32x4*)&lds[iv.w * TILE + (pw ^ (iv.w & 28))];
        f32x4 acc = a0 * wv.x + a1 * wv.y + a2 * wv.z + a3 * wv.w;
        f32x4* o = (f32x4*)(out + (size_t)b * NPOS + tile_base);
        o[lane] = acc;                       // cached store: L2 aggregates writebacks
    }
}

extern "C" void kernel_launch(void* const* d_in, const int* in_sizes, int n_in,
                              void* d_out, int out_size, void* d_ws, size_t ws_size,
                              hipStream_t stream) {
    const float* param = (const float*)d_in[0];
    const int*   sel   = (const int*)d_in[1];
    const float* prob  = (const float*)d_in[2];
    float*       out   = (float*)d_out;

    vparam_kernel<<<dim3(NPOS / TILE), dim3(BLK), 0, stream>>>(param, sel, prob, out);
}